// Round 4
// baseline (1046.207 us; speedup 1.0000x reference)
//
#include <hip/hip_runtime.h>
#include <stdint.h>

#define D 128
#define K1 384
#define TM 64
#define N_EDGES 800000
#define N_NODES 50000
#define NT (N_EDGES / TM)     // 12500 tiles
#define GRID 1024             // persistent blocks (4 per CU)

typedef __attribute__((ext_vector_type(8))) short short8;   // 8 bf16 = 4 VGPRs
typedef __attribute__((ext_vector_type(4))) float f32x4;
typedef unsigned int u32;

__device__ __forceinline__ u32 bf16_rne(float f) {
    u32 u = __builtin_bit_cast(u32, f);
    return (u + 0x7FFFu + ((u >> 16) & 1u)) >> 16;
}
__device__ __forceinline__ u32 pk2(float lo, float hi) {
    return bf16_rne(lo) | (bf16_rne(hi) << 16);
}

// async global->LDS DMA, 16B per lane; LDS dest = wave-uniform base + lane*16.
__device__ __forceinline__ void gl_lds16(const void* g, void* l) {
    __builtin_amdgcn_global_load_lds(
        (const __attribute__((address_space(1))) void*)g,
        (__attribute__((address_space(3))) void*)l,
        16, 0, 0);
}

// ---- prep: cell_attr fp32 -> bf16 (flat, vectorized) ----
__global__ void prep_cell(const float* __restrict__ src, unsigned short* __restrict__ dst, int n4) {
    int i = blockIdx.x * blockDim.x + threadIdx.x;
    if (i >= n4) return;
    float4 v = ((const float4*)src)[i];
    ushort4 o;
    o.x = (unsigned short)bf16_rne(v.x);
    o.y = (unsigned short)bf16_rne(v.y);
    o.z = (unsigned short)bf16_rne(v.z);
    o.w = (unsigned short)bf16_rne(v.w);
    ((ushort4*)dst)[i] = o;
}

// ---- prep: W1/W2 -> fragment-ordered bf16 (same layout as round 3) ----
__global__ void prep_w(const float* __restrict__ W1, const float* __restrict__ W2,
                       unsigned short* __restrict__ W1F, unsigned short* __restrict__ W2F) {
    int id = blockIdx.x * blockDim.x + threadIdx.x;   // 0 .. 65535
    if (id < K1 * D) {
        int k = id >> 7, n = id & 127;
        int c = k >> 7, kr = k & 127;
        int kk = kr >> 5, qq = (kr >> 3) & 3, e = k & 7;
        int TN = n >> 4, l16 = n & 15;
        int seg = ((c * 4 + kk) * 8 + TN) * 64 + qq * 16 + l16;
        W1F[seg * 8 + e] = (unsigned short)bf16_rne(W1[id]);
    } else {
        int id2 = id - K1 * D;
        int k = id2 >> 7, n = id2 & 127;
        int kk = k >> 5, qq = (k >> 3) & 3, e = k & 7;
        int TN = n >> 4, l16 = n & 15;
        int seg = (kk * 8 + TN) * 64 + qq * 16 + l16;
        W2F[seg * 8 + e] = (unsigned short)bf16_rne(W2[id2]);
    }
}

// ---- fused gather + MLP: persistent blocks, 4-phase ring over ~12 tiles ----
// bA: S then E.  bB: R then h.  4 barriers/tile; S(t+1) DMA'd during P4.
template <bool CELL_BF16>
__global__ __launch_bounds__(256, 4) void edge_mlp(
    const float* __restrict__ cell_f32,
    const unsigned short* __restrict__ cellb,
    const float* __restrict__ edge_attr,
    const unsigned short* __restrict__ W1F,
    const float* __restrict__ b1,
    const unsigned short* __restrict__ W2F,
    const float* __restrict__ b2,
    const int* __restrict__ sidx,
    const int* __restrict__ ridx,
    float* __restrict__ out)
{
    __shared__ __align__(16) unsigned short bA[TM * D];  // 16 KB
    __shared__ __align__(16) unsigned short bB[TM * D];  // 16 KB

    const int tid  = threadIdx.x;
    const int lane = tid & 63;
    const int wave = tid >> 6;     // col strip [wave*32, +32)
    const int l16  = lane & 15;
    const int q    = lane >> 4;
    const int rb   = tid >> 4;     // 0..15
    const int seg  = tid & 15;

    // ---- DMA gather: 4 instrs cover rows it*16+wave*4+{0..3}; swizzled source ----
    auto dma_cell = [&](const int* nidx, unsigned short* buf) {
#pragma unroll
        for (int it = 0; it < 4; ++it) {
            const int row = it * 16 + wave * 4 + q;
            const int srcoff = (l16 ^ (row & 7)) * 8;     // elems
            gl_lds16(cellb + (size_t)nidx[it] * D + srcoff,
                     (char*)buf + wave * 1024 + it * 4096);
        }
    };
    auto load_idx = [&](const int* __restrict__ idxp, int e0s, int* nidx) {
#pragma unroll
        for (int it = 0; it < 4; ++it)
            nidx[it] = idxp[e0s + it * 16 + wave * 4 + q];
    };
    // fallback (fp32 cell): reg-stage + cvt + swizzled write
    auto stage_f32 = [&](const int* __restrict__ idxp, int e0s, unsigned short* buf) {
#pragma unroll
        for (int it = 0; it < 4; ++it) {
            const int row = rb + it * 16;
            const int node = idxp[e0s + row];
            const float* src = cell_f32 + (size_t)node * D + seg * 8;
            float4 f0 = *(const float4*)src;
            float4 f1 = *(const float4*)(src + 4);
            uint4 v = make_uint4(pk2(f0.x, f0.y), pk2(f0.z, f0.w),
                                 pk2(f1.x, f1.y), pk2(f1.z, f1.w));
            *(uint4*)((char*)buf + row * 256 + ((seg ^ (row & 7)) * 16)) = v;
        }
    };

    short8 wf[4][2];               // time-multiplexed: c0 -> c1 -> c2 -> W2
    auto load_w1 = [&](int c) {
#pragma unroll
        for (int kk = 0; kk < 4; ++kk)
#pragma unroll
            for (int nt = 0; nt < 2; ++nt)
                wf[kk][nt] = *(const short8*)(W1F +
                    (size_t)(((c * 4 + kk) * 8 + wave * 2 + nt) * 64 + lane) * 8);
    };
    auto load_w2 = [&]() {
#pragma unroll
        for (int kk = 0; kk < 4; ++kk)
#pragma unroll
            for (int nt = 0; nt < 2; ++nt)
                wf[kk][nt] = *(const short8*)(W2F +
                    (size_t)((kk * 8 + wave * 2 + nt) * 64 + lane) * 8);
    };

    f32x4 acc[4][2];
    auto zero_acc = [&]() {
#pragma unroll
        for (int i = 0; i < 4; ++i)
#pragma unroll
            for (int j = 0; j < 2; ++j) acc[i][j] = (f32x4){0.f, 0.f, 0.f, 0.f};
    };
    auto compute_chunk = [&](const unsigned short* buf) {
#pragma unroll
        for (int kk = 0; kk < 4; ++kk)
#pragma unroll
            for (int mt = 0; mt < 4; ++mt) {
                const int row = mt * 16 + l16;
                short8 a = *(const short8*)((const char*)buf + row * 256 +
                                            (((kk * 4 + q) ^ (row & 7)) * 16));
                acc[mt][0] = __builtin_amdgcn_mfma_f32_16x16x32_bf16(wf[kk][0], a, acc[mt][0], 0, 0, 0);
                acc[mt][1] = __builtin_amdgcn_mfma_f32_16x16x32_bf16(wf[kk][1], a, acc[mt][1], 0, 0, 0);
            }
    };

    f32x4 b1v[2], b2v[2];
#pragma unroll
    for (int nt = 0; nt < 2; ++nt) {
        b1v[nt] = *(const f32x4*)(b1 + wave * 32 + nt * 16 + q * 4);
        b2v[nt] = *(const f32x4*)(b2 + wave * 32 + nt * 16 + q * 4);
    }

    int t = blockIdx.x;
    if (t >= NT) return;

    // ================= prologue: stage S(t0), wf <- c0 =================
    int nidxS[4], nidxR[4];
    if constexpr (CELL_BF16) {
        load_idx(sidx, t * TM, nidxS);
        dma_cell(nidxS, bA);
        load_idx(ridx, t * TM, nidxR);
    } else {
        stage_f32(sidx, t * TM, bA);
    }
    load_w1(0);
    __syncthreads();                           // S in bA; wf = c0

    for (;;) {
        const int e0 = t * TM;
        const int tn = t + GRID;
        const bool more = tn < NT;
        zero_acc();

        // ================= P1: c0(bA=S) | DMA R->bB | edge half1 =================
        if constexpr (CELL_BF16) dma_cell(nidxR, bB);
        else                     stage_f32(ridx, e0, bB);
        float4 ef[8];
#pragma unroll
        for (int it = 0; it < 2; ++it) {       // half1: rows rb, rb+16
            const float* src = edge_attr + (size_t)(e0 + rb + it * 16) * D + seg * 8;
            ef[it * 2]     = *(const float4*)src;
            ef[it * 2 + 1] = *(const float4*)(src + 4);
        }
        compute_chunk(bA);                     // c0
        load_w1(1);                            // wf <- c1
        __syncthreads();                       // R ready in bB

        // ================= P2: c1(bB=R) | edge half2 | E->bA =================
#pragma unroll
        for (int it = 2; it < 4; ++it) {       // half2: rows rb+32, rb+48
            const float* src = edge_attr + (size_t)(e0 + rb + it * 16) * D + seg * 8;
            ef[it * 2]     = *(const float4*)src;
            ef[it * 2 + 1] = *(const float4*)(src + 4);
        }
        // cvt half1 early (frees regs; covered by c0)
        uint4 evA[2];
#pragma unroll
        for (int it = 0; it < 2; ++it)
            evA[it] = make_uint4(pk2(ef[it*2].x, ef[it*2].y),   pk2(ef[it*2].z, ef[it*2].w),
                                 pk2(ef[it*2+1].x, ef[it*2+1].y), pk2(ef[it*2+1].z, ef[it*2+1].w));
        compute_chunk(bB);                     // c1
#pragma unroll
        for (int it = 0; it < 2; ++it) {       // write E half1 (bA free after P1 sync)
            const int row = rb + it * 16;
            *(uint4*)((char*)bA + row * 256 + ((seg ^ (row & 7)) * 16)) = evA[it];
        }
#pragma unroll
        for (int it = 2; it < 4; ++it) {       // cvt + write E half2 (covered by c1)
            const int row = rb + it * 16;
            uint4 v = make_uint4(pk2(ef[it*2].x, ef[it*2].y),   pk2(ef[it*2].z, ef[it*2].w),
                                 pk2(ef[it*2+1].x, ef[it*2+1].y), pk2(ef[it*2+1].z, ef[it*2+1].w));
            *(uint4*)((char*)bA + row * 256 + ((seg ^ (row & 7)) * 16)) = v;
        }
        load_w1(2);                            // wf <- c2
        __syncthreads();                       // E ready in bA

        // ================= P3: c2(bA=E) | h->bB | prefetch next S idx =================
        compute_chunk(bA);                     // c2
        if (more) {
            if constexpr (CELL_BF16) load_idx(sidx, tn * TM, nidxS);
        }
#pragma unroll
        for (int mt = 0; mt < 4; ++mt)         // h = relu(acc+b1) -> bB (8B swizzled)
#pragma unroll
            for (int nt = 0; nt < 2; ++nt) {
                f32x4 v = acc[mt][nt] + b1v[nt];
#pragma unroll
                for (int r = 0; r < 4; ++r) v[r] = v[r] > 0.f ? v[r] : 0.f;
                const int M = mt * 16 + l16;
                const int slot = (wave * 4 + nt * 2 + (q >> 1)) ^ (M & 7);
                *(uint2*)((char*)bB + M * 256 + slot * 16 + (q & 1) * 8) =
                    make_uint2(pk2(v[0], v[1]), pk2(v[2], v[3]));
            }
        load_w2();                             // wf <- W2
        __syncthreads();                       // h ready in bB

        // ================= P4: GEMM2(bB=h) | DMA S(t+1)->bA | stores =================
        if (more) {
            if constexpr (CELL_BF16) dma_cell(nidxS, bA);
            else                     stage_f32(sidx, tn * TM, bA);
        }
        zero_acc();                            // reuse acc as acc2
#pragma unroll
        for (int kk = 0; kk < 4; ++kk)
#pragma unroll
            for (int mt = 0; mt < 4; ++mt) {
                const int row = mt * 16 + l16;
                short8 h = *(const short8*)((const char*)bB + row * 256 +
                                            (((kk * 4 + q) ^ (row & 7)) * 16));
                acc[mt][0] = __builtin_amdgcn_mfma_f32_16x16x32_bf16(wf[kk][0], h, acc[mt][0], 0, 0, 0);
                acc[mt][1] = __builtin_amdgcn_mfma_f32_16x16x32_bf16(wf[kk][1], h, acc[mt][1], 0, 0, 0);
            }
        if (more) {
            if constexpr (CELL_BF16) load_idx(ridx, tn * TM, nidxR);
        }
#pragma unroll
        for (int mt = 0; mt < 4; ++mt)
#pragma unroll
            for (int nt = 0; nt < 2; ++nt) {
                f32x4 o = acc[mt][nt] + b2v[nt];
                *(f32x4*)(out + (size_t)(e0 + mt * 16 + l16) * D + wave * 32 + nt * 16 + q * 4) = o;
            }
        if (more) load_w1(0);                  // wf <- c0 for next tile
        __syncthreads();                       // drains S-DMA; bA = S(t+1)
        if (!more) break;
        t = tn;
    }
}

extern "C" void kernel_launch(void* const* d_in, const int* in_sizes, int n_in,
                              void* d_out, int out_size, void* d_ws, size_t ws_size,
                              hipStream_t stream) {
    const float* cell = (const float*)d_in[0];
    const float* edge = (const float*)d_in[1];
    const float* W1   = (const float*)d_in[2];
    const float* b1   = (const float*)d_in[3];
    const float* W2   = (const float*)d_in[4];
    const float* b2   = (const float*)d_in[5];
    const int*   eidx = (const int*)d_in[6];

    const size_t cell_bytes = (size_t)N_NODES * D * 2;      // 12.8 MB
    const size_t w1f_bytes  = (size_t)K1 * D * 2;           // 98304
    const size_t w2f_bytes  = (size_t)D * D * 2;            // 32768

    bool cell_in_ws = ws_size >= cell_bytes + w1f_bytes + w2f_bytes;
    unsigned short* cellb;
    unsigned short* W1F;
    if (cell_in_ws) {
        cellb = (unsigned short*)d_ws;
        W1F   = (unsigned short*)((char*)d_ws + cell_bytes);
    } else {
        cellb = nullptr;
        W1F   = (unsigned short*)d_ws;
    }
    unsigned short* W2F = W1F + K1 * D;

    if (cell_in_ws) {
        int n4 = N_NODES * D / 4;   // 1.6M float4s
        prep_cell<<<(n4 + 255) / 256, 256, 0, stream>>>(cell, cellb, n4);
    }
    prep_w<<<(K1 * D + D * D) / 256, 256, 0, stream>>>(W1, W2, W1F, W2F);

    const int* sidx = eidx;
    const int* ridx = eidx + N_EDGES;
    if (cell_in_ws) {
        edge_mlp<true><<<GRID, 256, 0, stream>>>(
            cell, cellb, edge, W1F, b1, W2F, b2, sidx, ridx, (float*)d_out);
    } else {
        edge_mlp<false><<<GRID, 256, 0, stream>>>(
            cell, cellb, edge, W1F, b1, W2F, b2, sidx, ridx, (float*)d_out);
    }
}